// Round 7
// baseline (68.549 us; speedup 1.0000x reference)
//
#include <hip/hip_runtime.h>
#include <math.h>

#define B_ 1000
#define D_ 8
#define PRE_ 98
#define NXT_ 2048
#define J_ 32
#define K_ 64
#define A_ 5

typedef __attribute__((ext_vector_type(8))) __bf16 bf16x8;
typedef __attribute__((ext_vector_type(4))) float f32x4;
typedef __attribute__((ext_vector_type(16))) float f32x16;

__device__ __forceinline__ unsigned cvtpk(float lo, float hi) {
  unsigned r;
  asm("v_cvt_pk_bf16_f32 %0, %1, %2" : "=v"(r) : "v"(lo), "v"(hi));
  return r;
}

union bfu { unsigned u[4]; bf16x8 v; };

__device__ __forceinline__ bf16x8 pk8(float a0, float a1, float a2, float a3,
                                      float a4, float a5, float a6, float a7) {
  bfu r;
  r.u[0] = cvtpk(a0, a1);
  r.u[1] = cvtpk(a2, a3);
  r.u[2] = cvtpk(a4, a5);
  r.u[3] = cvtpk(a6, a7);
  return r.v;
}

__device__ __forceinline__ bf16x8 ld8(const float* p) {
  float2 a = *(const float2*)(p);
  float2 b = *(const float2*)(p + 2);
  float2 c = *(const float2*)(p + 4);
  float2 d = *(const float2*)(p + 6);
  return pk8(a.x, a.y, b.x, b.y, c.x, c.y, d.x, d.y);
}

// k-range [96,112): k=96,97 real, k=98 = folded extra (bias / 1.0), rest 0.
__device__ __forceinline__ bf16x8 ld_tail(const float* p96, float extra,
                                          bool hi0) {
  bfu r;
  if (hi0) {
    float2 a = *(const float2*)(p96);
    r.u[0] = cvtpk(a.x, a.y);
    r.u[1] = cvtpk(extra, 0.0f);
  } else {
    r.u[0] = 0u;
    r.u[1] = 0u;
  }
  r.u[2] = 0u;
  r.u[3] = 0u;
  return r.v;
}

// ws layout (float offsets):
//   [0, 4194304)   S1part[ocp(16)][1024 b][8 d][32 j] f32 (coalesced writes)
//   [4194304, +4096) spsum  (slot = blockId*4 + wave)
//   [4198400, +4096) spsq
//   [4202496, +2048) wcp[(d*32+j)*8 + oc]  Wc row-sum partials

// 1024 blocks (d:8 x bt:16 x oc:8), 256 thr, 4 blocks/CU.
// Direct f32 gather + in-register bf16 convert (no staging kernel, no LDS
// pipeline, no barriers in the main path). GEMM1 K=112 (7 MFMA), GEMM2 in-reg.
__global__ __launch_bounds__(256, 4) void kA(
    const float* __restrict__ x, const float* __restrict__ W1,
    const float* __restrict__ b1, const float* __restrict__ Wc,
    float* __restrict__ S1part, float* __restrict__ spsum,
    float* __restrict__ spsq, float* __restrict__ wcp) {
  __shared__ float T[4][32 * 33];  // wave-private transpose tiles
  __shared__ float WS[8][33];      // wcsum partial reduce (bt==0 blocks only)

  const int id = blockIdx.x;
  const int d = id & 7;  // XCD-affine heuristic
  const int rest = id >> 3;
  const int bt = rest & 15, oc = rest >> 4;
  const int tid = threadIdx.x;
  const int w = tid >> 6, lane = tid & 63;
  const int bh = w & 1, ohh = w >> 1;
  const int l31 = lane & 31, hi = lane >> 5;
  const bool lo_half = (hi == 0);

  // ---- x fragments: lane = column b, gathered f32 -> bf16 (k=98 -> 1.0) ----
  const int bg = bt * 2 + bh;
  const int b = bg * 32 + l31;
  const float* xrow =
      x + (size_t)(b < B_ ? b : B_ - 1) * (D_ * PRE_) + d * PRE_;
  bf16x8 xf[7];
#pragma unroll
  for (int ks = 0; ks < 6; ++ks) xf[ks] = ld8(xrow + ks * 16 + hi * 8);
  xf[6] = ld_tail(xrow + 96, 1.0f, lo_half);
  if (b >= B_) {
    bfu z;
    z.u[0] = z.u[1] = z.u[2] = z.u[3] = 0u;
#pragma unroll
    for (int ks = 0; ks < 7; ++ks) xf[ks] = z.v;
  }

  const int og0 = oc * 8 + ohh * 4;
  const float* wcrow = Wc + ((size_t)d * J_ + l31) * NXT_;  // j = l31

  f32x16 acc2 = {};
  float lsum = 0.0f, lsq = 0.0f;

#pragma unroll
  for (int ou = 0; ou < 4; ++ou) {
    const int og = og0 + ou;
    const int o = og * 32 + l31;
    const float* wrow = W1 + (size_t)(d * NXT_ + o) * PRE_;
    const float bias = b1[d * NXT_ + o];

    // Wc fragments for GEMM2 (f32 gather, 16B-aligned float4)
    bf16x8 wc0, wc1;
    {
      const float* p = wcrow + og * 32 + hi * 8;
      float4 q0 = *(const float4*)(p);
      float4 q1 = *(const float4*)(p + 4);
      wc0 = pk8(q0.x, q0.y, q0.z, q0.w, q1.x, q1.y, q1.z, q1.w);
      float4 r0 = *(const float4*)(p + 16);
      float4 r1 = *(const float4*)(p + 20);
      wc1 = pk8(r0.x, r0.y, r0.z, r0.w, r1.x, r1.y, r1.z, r1.w);
    }

    // GEMM1: C[o][b] 32x32, K=112 (k>=112 provably zero -> skipped)
    f32x16 acc = {};
#pragma unroll
    for (int ks = 0; ks < 6; ++ks) {
      bf16x8 a = ld8(wrow + ks * 16 + hi * 8);
      acc = __builtin_amdgcn_mfma_f32_32x32x16_bf16(a, xf[ks], acc, 0, 0, 0);
    }
    {
      bf16x8 a = ld_tail(wrow + 96, bias, lo_half);
      acc = __builtin_amdgcn_mfma_f32_32x32x16_bf16(a, xf[6], acc, 0, 0, 0);
    }

    // epilogue: relu + stats + in-register P frags -> GEMM2 (verbatim R6)
    float v[16];
#pragma unroll
    for (int r = 0; r < 16; ++r) {
      v[r] = fmaxf(acc[r], 0.0f);
      lsum += v[r];
      lsq = fmaf(v[r], v[r], lsq);
    }
#pragma unroll
    for (int t = 0; t < 2; ++t) {
      unsigned A0 = cvtpk(v[8 * t + 0], v[8 * t + 1]);
      unsigned A1 = cvtpk(v[8 * t + 2], v[8 * t + 3]);
      unsigned B0 = cvtpk(v[8 * t + 4], v[8 * t + 5]);
      unsigned B1 = cvtpk(v[8 * t + 6], v[8 * t + 7]);
      unsigned sA0 = __shfl_xor(A0, 32);
      unsigned sA1 = __shfl_xor(A1, 32);
      unsigned sB0 = __shfl_xor(B0, 32);
      unsigned sB1 = __shfl_xor(B1, 32);
      bfu f;
      f.u[0] = lo_half ? A0 : sB0;
      f.u[1] = lo_half ? A1 : sB1;
      f.u[2] = lo_half ? sA0 : B0;
      f.u[3] = lo_half ? sA1 : B1;
      acc2 = __builtin_amdgcn_mfma_f32_32x32x16_bf16(t == 0 ? wc0 : wc1, f.v,
                                                     acc2, 0, 0, 0);
    }
  }

  // ---- coalesced S1part store via wave-private LDS transpose ----
  {
    float* tw = T[w];
#pragma unroll
    for (int r = 0; r < 16; ++r) {
      int j = (r & 3) + 8 * (r >> 2) + 4 * hi;
      tw[l31 * 33 + j] = acc2[r];  // l31 = local b-row
    }
    const int ocp = oc * 2 + ohh;
    const size_t base = (((size_t)ocp * 1024 + bg * 32) * 8 + d) * 32;
#pragma unroll
    for (int bb = 0; bb < 16; ++bb) {
      int brow = bb * 2 + hi;
      S1part[base + (size_t)brow * 256 + l31] = tw[brow * 33 + l31];
    }
  }

  // ---- stats: per-wave shuffle reduction ----
#pragma unroll
  for (int off = 32; off; off >>= 1) {
    lsum += __shfl_down(lsum, off);
    lsq += __shfl_down(lsq, off);
  }
  if (lane == 0) {
    spsum[id * 4 + w] = lsum;
    spsq[id * 4 + w] = lsq;
  }

  // ---- wcsum partials (64 blocks: bt == 0) ----
  if (bt == 0) {
    const int j = tid & 31, seg = tid >> 5;
    const float* wr = Wc + ((size_t)d * J_ + j) * NXT_ + oc * 256 + seg * 32;
    float s = 0.0f;
#pragma unroll
    for (int i = 0; i < 32; ++i) s += wr[i];
    WS[seg][j] = s;
    __syncthreads();
    if (tid < 32) {
      float t = 0.0f;
#pragma unroll
      for (int g = 0; g < 8; ++g) t += WS[g][tid];
      wcp[((size_t)d * 32 + tid) * 8 + oc] = t;
    }
  }
}

#define W3S 33
#define W4S 99

__global__ __launch_bounds__(256) void kB(
    const float* __restrict__ S1part, const float* __restrict__ spsum,
    const float* __restrict__ spsq, const float* __restrict__ wcp,
    const float* __restrict__ bc, const float* __restrict__ b_mat,
    const float* __restrict__ h_mat, const float* __restrict__ a_mat,
    const float* __restrict__ noise, const float* __restrict__ indicator,
    const float* __restrict__ cutb, const float* __restrict__ W3,
    const float* __restrict__ b3, const float* __restrict__ W4,
    const float* __restrict__ b4, const float* __restrict__ Wo,
    const float* __restrict__ bo, float* __restrict__ out) {
  __shared__ float W3l[98 * W3S];
  __shared__ float W4l[49 * W4S];
  __shared__ float Wol[10 * 49];
  __shared__ float b3l[98], b4l[49], bol[10];
  __shared__ float cutl[32], coefl[256], konstl[32], wcs[256];
  __shared__ float psum[8][33], psq[8][33];
  __shared__ float mvals[8], vvals[8];
  __shared__ float sh_gm, sh_inv;
  __shared__ float offs[D_][J_];
  __shared__ float h1[8][32];
  __shared__ float h2[8][100];
  __shared__ float h3[8][52];
  __shared__ float lg[8][10];
  __shared__ float lsel[8];

  const int tid = threadIdx.x;

  for (int idx = tid; idx < 98 * 32; idx += 256) {
    int o = idx >> 5, j = idx & 31;
    W3l[o * W3S + j] = W3[idx];
  }
  for (int idx = tid; idx < 49 * 98; idx += 256) {
    int o = idx / 98, k = idx - o * 98;
    W4l[o * W4S + k] = W4[idx];
  }
  for (int idx = tid; idx < 490; idx += 256) Wol[idx] = Wo[idx];
  if (tid < 98) b3l[tid] = b3[tid];
  if (tid < 49) b4l[tid] = b4[tid];
  if (tid < 10) bol[tid] = bo[tid];
  if (tid < 32) cutl[tid] = cutb[tid];

  // wcsum finalize: tid = d*32+j
  {
    float s = 0.0f;
    const float* p = wcp + (size_t)tid * 8;
#pragma unroll
    for (int o8 = 0; o8 < 8; ++o8) s += p[o8];
    wcs[tid] = s;
  }

  // stats reduce: 256 threads x 16 loads
  {
    int dd = tid >> 5, i = tid & 31;
    float s = 0.0f, q = 0.0f;
#pragma unroll
    for (int m = 0; m < 4; ++m) {
      int k = i + m * 32;
      int base = (k * 8 + dd) * 4;
#pragma unroll
      for (int ww = 0; ww < 4; ++ww) {
        s += spsum[base + ww];
        q += spsq[base + ww];
      }
    }
    psum[dd][i] = s;
    psq[dd][i] = q;
  }
  __syncthreads();
  if (tid < 8) {
    float s = 0.0f, q = 0.0f;
#pragma unroll
    for (int i = 0; i < 32; ++i) {
      s += psum[tid][i];
      q += psq[tid][i];
    }
    const float inv_cnt = 1.0f / ((float)B_ * (float)NXT_);
    float m = s * inv_cnt;
    mvals[tid] = m;
    vvals[tid] = q * inv_cnt - m * m;
  }
  __syncthreads();
  if (tid == 0) {
    float gm = 0.0f, gv = 0.0f;
    for (int dd = 0; dd < 8; ++dd) {
      gm += mvals[dd];
      gv += vvals[dd];
    }
    gm *= 0.125f;
    gv *= 0.125f;
    sh_gm = gm;
    sh_inv = 1.0f / sqrtf(gv + 1e-6f);
  }
  __syncthreads();
  {
    int dd = tid >> 5, j = tid & 31;
    float hs[A_] = {0, 0, 0, 0, 0};
    for (int k = 0; k < K_; ++k) {
      float indv = indicator[j * K_ + k];
      if (indv != 0.0f) {
        const float* hp = h_mat + ((size_t)dd * K_ + k) * A_;
#pragma unroll
        for (int a = 0; a < A_; ++a) hs[a] = fmaf(indv, hp[a], hs[a]);
      }
    }
    float hv = 0.0f;
#pragma unroll
    for (int a = 0; a < A_; ++a) hv = fmaf(hs[a], a_mat[j * A_ + a], hv);
    float c = b_mat[dd * J_ + j] * hv;
    coefl[tid] = c * sh_inv;
    offs[dd][j] = c * (bc[dd * J_ + j] - sh_gm * wcs[tid] * sh_inv);
  }
  __syncthreads();
  if (tid < J_) {
    float nz = 0.0f;
#pragma unroll
    for (int a = 0; a < A_; ++a)
      nz = fmaf(a_mat[tid * A_ + a], noise[tid * A_ + a], nz);
    float s = nz;
#pragma unroll
    for (int dd = 0; dd < D_; ++dd) s += offs[dd][tid];
    konstl[tid] = s;
  }
  __syncthreads();

  const int row = tid >> 5, lane = tid & 31;
  const int b = blockIdx.x * 8 + row;  // 125*8 = 1000 exactly

  float rsum = konstl[lane];
#pragma unroll
  for (int dd = 0; dd < D_; ++dd) {
    float s = 0.0f;
#pragma unroll
    for (int p = 0; p < 16; ++p)
      s += S1part[(((size_t)p * 1024 + b) * 8 + dd) * 32 + lane];
    rsum = fmaf(coefl[dd * J_ + lane], s, rsum);
  }
  h1[row][lane] = fmaxf(rsum + cutl[lane], 0.0f);
  __syncthreads();

  for (int o = lane; o < 98; o += 32) {
    float a = b3l[o];
#pragma unroll
    for (int j = 0; j < 32; ++j) a = fmaf(h1[row][j], W3l[o * W3S + j], a);
    h2[row][o] = fmaxf(a, 0.0f);
  }
  __syncthreads();

  for (int o = lane; o < 49; o += 32) {
    float a = b4l[o];
    for (int k = 0; k < 98; ++k) a = fmaf(h2[row][k], W4l[o * W4S + k], a);
    h3[row][o] = fmaxf(a, 0.0f);
  }
  __syncthreads();

  if (lane < 10) {
    float a = bol[lane];
#pragma unroll
    for (int k = 0; k < 49; ++k) a = fmaf(h3[row][k], Wol[lane * 49 + k], a);
    lg[row][lane] = a;
  }
  __syncthreads();
  if (lane == 0) {
    float mx = lg[row][0];
    for (int i = 1; i < 10; ++i) mx = fmaxf(mx, lg[row][i]);
    float se = 0.0f;
    for (int i = 0; i < 10; ++i) se += expf(lg[row][i] - mx);
    lsel[row] = mx + logf(se);
  }
  __syncthreads();
  if (lane < 10) out[(size_t)b * 10 + lane] = lg[row][lane] - lsel[row];
}

extern "C" void kernel_launch(void* const* d_in, const int* in_sizes, int n_in,
                              void* d_out, int out_size, void* d_ws,
                              size_t ws_size, hipStream_t stream) {
  const float* x = (const float*)d_in[0];
  const float* W1 = (const float*)d_in[1];
  const float* b1 = (const float*)d_in[2];
  const float* Wc = (const float*)d_in[3];
  const float* bc = (const float*)d_in[4];
  const float* cutb = (const float*)d_in[5];
  const float* bmat = (const float*)d_in[6];
  const float* hmat = (const float*)d_in[7];
  const float* amat = (const float*)d_in[8];
  const float* noise = (const float*)d_in[9];
  const float* W3 = (const float*)d_in[10];
  const float* b3 = (const float*)d_in[11];
  const float* W4 = (const float*)d_in[12];
  const float* b4 = (const float*)d_in[13];
  const float* Wo = (const float*)d_in[14];
  const float* bo = (const float*)d_in[15];

  float* ws = (float*)d_ws;
  float* S1part = ws;            // [0, 4194304)
  float* spsum = ws + 4194304;   // 4096
  float* spsq = ws + 4198400;    // 4096
  float* wcp = ws + 4202496;     // 2048

  kA<<<1024, 256, 0, stream>>>(x, W1, b1, Wc, S1part, spsum, spsq, wcp);
  kB<<<125, 256, 0, stream>>>(S1part, spsum, spsq, wcp, bc, bmat, hmat, amat,
                              noise, (const float*)d_in[16], cutb, W3, b3, W4,
                              b4, Wo, bo, (float*)d_out);
}

// Round 9
// 43.013 us; speedup vs baseline: 1.5937x; 1.5937x over previous
//
#include <hip/hip_runtime.h>
#include <math.h>

#define B_ 1000
#define D_ 8
#define PRE_ 98
#define NXT_ 2048
#define J_ 32
#define K_ 64
#define A_ 5

typedef __attribute__((ext_vector_type(8))) __bf16 bf16x8;
typedef __attribute__((ext_vector_type(4))) float f32x4;
typedef __attribute__((ext_vector_type(16))) float f32x16;
typedef __attribute__((ext_vector_type(8))) unsigned short us8;

__device__ __forceinline__ unsigned cvtpk(float lo, float hi) {
  unsigned r;
  asm("v_cvt_pk_bf16_f32 %0, %1, %2" : "=v"(r) : "v"(lo), "v"(hi));
  return r;
}

union bfu { unsigned u[4]; bf16x8 v; };

// ws layout (float offsets):
//   [0, 1048576)        S1part[oc4][1024 b][8 d][32 j] f32  (4 MB, final j-partials)
//   [1048576, 1966080)  w1a: frag fi=(d*64+og)*7+ks; us8 slot = fi*512 + lane*8
//                       lane l: o=og*32+(l&31), k=ks*16+(l>>5)*8  (k=98 -> b1, k>98 -> 0)
//   [1966080, 2424832)  xa:  fi=(d*32+bg)*7+ks; b=bg*32+(l&31)    (k=98 -> 1.0; b>=1000 -> 0)
//   [2424832, 2686976)  wca: fi=(d*64+og)*2+t2; j=l&31, o=og*32+t2*16+(l>>5)*8
//   [2686976, +4096)    spsum (slot = blockId*4 + wave)
//   [2691072, +4096)    spsq
//   [2695168, +2048)    wcp[(d*32+j)*8 + oq]

// 832 blocks: [0,512) W1 transpose, [512,768) x transpose, [768,832) Wc (+wcsum)
__global__ __launch_bounds__(256) void kcvt(
    const float* __restrict__ x, const float* __restrict__ W1,
    const float* __restrict__ b1, const float* __restrict__ Wc,
    unsigned short* __restrict__ w1a, unsigned short* __restrict__ xa,
    unsigned short* __restrict__ wca, float* __restrict__ wcp) {
  __shared__ float sbuf[32 * 257];  // row-major staging
  __shared__ float extra[32];       // bias / unused
  __shared__ float ws2[32][9];      // wcsum 8->1 reduce

  const int bid = blockIdx.x, tid = threadIdx.x;

  if (bid < 512) {  // ---- W1: tile (d, og) = 32 rows x 98 k ----
    const int d = bid & 7, og = bid >> 3;
    const float* base = W1 + ((size_t)d * NXT_ + og * 32) * PRE_;
    for (int idx = tid; idx < 32 * 98; idx += 256) {
      int r = idx / 98, k = idx - r * 98;
      sbuf[r * 99 + k] = base[idx];
    }
    if (tid < 32) extra[tid] = b1[d * NXT_ + og * 32 + tid];
    __syncthreads();
    unsigned short* dst = w1a + (size_t)((d * 64 + og) * 7) * 512;
#pragma unroll
    for (int q = 0; q < 2; ++q) {
      int s = tid + q * 256;
      if (s < 448) {
        int ks = s >> 6, l = s & 63;
        int r = l & 31, k0 = ks * 16 + (l >> 5) * 8;
        const float* row = sbuf + r * 99;
        bfu v;
#pragma unroll
        for (int p = 0; p < 4; ++p) {
          int k = k0 + 2 * p;
          float f0 = (k < 98) ? row[k] : ((k == 98) ? extra[r] : 0.0f);
          float f1 = (k + 1 < 98) ? row[k + 1] : ((k + 1 == 98) ? extra[r] : 0.0f);
          v.u[p] = cvtpk(f0, f1);
        }
        *(bf16x8*)(dst + (size_t)s * 8) = v.v;
      }
    }
  } else if (bid < 768) {  // ---- x: tile (d, bg) = 32 rows x 98 k ----
    const int b2 = bid - 512;
    const int d = b2 & 7, bg = b2 >> 3;
    for (int idx = tid; idx < 32 * 98; idx += 256) {
      int r = idx / 98, k = idx - r * 98;
      int gb = bg * 32 + r;
      sbuf[r * 99 + k] =
          (gb < B_) ? x[(size_t)gb * (D_ * PRE_) + d * PRE_ + k] : 0.0f;
    }
    __syncthreads();
    unsigned short* dst = xa + (size_t)((d * 32 + bg) * 7) * 512;
#pragma unroll
    for (int q = 0; q < 2; ++q) {
      int s = tid + q * 256;
      if (s < 448) {
        int ks = s >> 6, l = s & 63;
        int r = l & 31, k0 = ks * 16 + (l >> 5) * 8;
        bool valid = (bg * 32 + r) < B_;
        const float* row = sbuf + r * 99;
        bfu v;
#pragma unroll
        for (int p = 0; p < 4; ++p) {
          int k = k0 + 2 * p;
          float f0 = 0.0f, f1 = 0.0f;
          if (valid) {
            f0 = (k < 98) ? row[k] : ((k == 98) ? 1.0f : 0.0f);
            f1 = (k + 1 < 98) ? row[k + 1] : ((k + 1 == 98) ? 1.0f : 0.0f);
          }
          v.u[p] = cvtpk(f0, f1);
        }
        *(bf16x8*)(dst + (size_t)s * 8) = v.v;
      }
    }
  } else {  // ---- Wc: tile (d, oq) = 32 j-rows x 256 o ----
    const int b3 = bid - 768;
    const int d = b3 & 7, oq = b3 >> 3;
    for (int idx = tid; idx < 32 * 256; idx += 256) {
      int j = idx >> 8, o = idx & 255;
      sbuf[j * 257 + o] = Wc[((size_t)d * J_ + j) * NXT_ + oq * 256 + o];
    }
    __syncthreads();
    // fragments: og in [oq*8, oq*8+8)
    unsigned short* dst = wca + (size_t)((d * 64 + oq * 8) * 2) * 512;
#pragma unroll
    for (int q = 0; q < 4; ++q) {
      int s = tid + q * 256;  // [0,1024): og_loc(8) x t2(2) x lane(64)
      int ogl = s >> 7, t2 = (s >> 6) & 1, l = s & 63;
      int j = l & 31;
      int ol = ogl * 32 + t2 * 16 + (l >> 5) * 8;
      const float* row = sbuf + j * 257 + ol;
      bfu v;
#pragma unroll
      for (int p = 0; p < 4; ++p) v.u[p] = cvtpk(row[2 * p], row[2 * p + 1]);
      *(bf16x8*)(dst + (size_t)s * 8) = v.v;
    }
    // wcsum partial for this (d, oq): j = tid>>3, 8-seg reduce
    {
      int j = tid >> 3, seg = tid & 7;
      const float* row = sbuf + j * 257 + seg * 32;
      float sacc = 0.0f;
#pragma unroll
      for (int i = 0; i < 32; ++i) sacc += row[i];
      ws2[j][seg] = sacc;
    }
    __syncthreads();
    if (tid < 32) {
      float t = 0.0f;
#pragma unroll
      for (int g = 0; g < 8; ++g) t += ws2[tid][g];
      wcp[((size_t)d * 32 + tid) * 8 + oq] = t;
    }
  }
}

// 1024 blocks (d:8 x bg:32 x oc:4), 256 thr, 4 blocks/CU, coalesced reg-frag
// loads only, ONE barrier (final 4-wave reduce -> 4MB S1part, coalesced).
__global__ __launch_bounds__(256, 4) void k1(
    const unsigned short* __restrict__ w1a,
    const unsigned short* __restrict__ xa,
    const unsigned short* __restrict__ wca, float* __restrict__ S1part,
    float* __restrict__ spsum, float* __restrict__ spsq) {
  __shared__ float red[4][32 * 33];  // per-wave transposed 32x32 tiles

  const int id = blockIdx.x;
  const int d = id & 7;  // XCD-pinned
  const int r2 = id >> 3;
  const int bg = r2 & 31, oc = r2 >> 5;  // oc in [0,4)
  const int tid = threadIdx.x;
  const int w = tid >> 6, lane = tid & 63;
  const int l31 = lane & 31, hi = lane >> 5;
  const bool lo_half = (hi == 0);

  // x fragments (7 = K112/16), reused across all 16 og of this wave
  bf16x8 xf[7];
  {
    const unsigned short* xb =
        xa + (size_t)((d * 32 + bg) * 7) * 512 + lane * 8;
#pragma unroll
    for (int ks = 0; ks < 7; ++ks) xf[ks] = *(const bf16x8*)(xb + ks * 512);
  }

  f32x16 acc2 = {};
  float lsum = 0.0f, lsq = 0.0f;

#pragma unroll 2
  for (int i = 0; i < 4; ++i) {
    const int og = oc * 16 + w * 4 + i;
    const unsigned short* ab =
        w1a + (size_t)((d * 64 + og) * 7) * 512 + lane * 8;
    const unsigned short* wb =
        wca + (size_t)((d * 64 + og) * 2) * 512 + lane * 8;
    bf16x8 wc0 = *(const bf16x8*)(wb);
    bf16x8 wc1 = *(const bf16x8*)(wb + 512);

    // GEMM1: C[o][b] 32x32, K=112
    f32x16 acc = {};
#pragma unroll
    for (int ks = 0; ks < 7; ++ks) {
      bf16x8 a = *(const bf16x8*)(ab + ks * 512);
      acc = __builtin_amdgcn_mfma_f32_32x32x16_bf16(a, xf[ks], acc, 0, 0, 0);
    }

    // epilogue: relu + stats + in-register P frags -> GEMM2 (verified lane math)
    float v[16];
#pragma unroll
    for (int r = 0; r < 16; ++r) {
      v[r] = fmaxf(acc[r], 0.0f);
      lsum += v[r];
      lsq = fmaf(v[r], v[r], lsq);
    }
#pragma unroll
    for (int t = 0; t < 2; ++t) {
      unsigned A0 = cvtpk(v[8 * t + 0], v[8 * t + 1]);
      unsigned A1 = cvtpk(v[8 * t + 2], v[8 * t + 3]);
      unsigned B0 = cvtpk(v[8 * t + 4], v[8 * t + 5]);
      unsigned B1 = cvtpk(v[8 * t + 6], v[8 * t + 7]);
      unsigned sA0 = __shfl_xor(A0, 32);
      unsigned sA1 = __shfl_xor(A1, 32);
      unsigned sB0 = __shfl_xor(B0, 32);
      unsigned sB1 = __shfl_xor(B1, 32);
      bfu f;
      f.u[0] = lo_half ? A0 : sB0;
      f.u[1] = lo_half ? A1 : sB1;
      f.u[2] = lo_half ? sA0 : B0;
      f.u[3] = lo_half ? sA1 : B1;
      acc2 = __builtin_amdgcn_mfma_f32_32x32x16_bf16(t == 0 ? wc0 : wc1, f.v,
                                                     acc2, 0, 0, 0);
    }
  }

  // park transposed tile: red[w][b_local][j]
  {
    float* tw = red[w];
#pragma unroll
    for (int r = 0; r < 16; ++r) {
      int j = (r & 3) + 8 * (r >> 2) + 4 * hi;
      tw[l31 * 33 + j] = acc2[r];
    }
  }
  __syncthreads();

  // sum 4 waves, write final oc-partial coalesced: 4 (row,j4) pairs/thread
  {
    const int row = tid >> 3, j0 = (tid & 7) * 4;
    f32x4 s;
#pragma unroll
    for (int e = 0; e < 4; ++e) {
      float acc_ = 0.0f;
#pragma unroll
      for (int ww = 0; ww < 4; ++ww) acc_ += red[ww][row * 33 + j0 + e];
      s[e] = acc_;
    }
    const int b = bg * 32 + row;
    *(f32x4*)(S1part + (((size_t)oc * 1024 + b) * 8 + d) * 32 + j0) = s;
  }

  // stats: per-wave shuffle reduction
#pragma unroll
  for (int off = 32; off; off >>= 1) {
    lsum += __shfl_down(lsum, off);
    lsq += __shfl_down(lsq, off);
  }
  if (lane == 0) {
    spsum[id * 4 + w] = lsum;
    spsq[id * 4 + w] = lsq;
  }
}

#define W3S 33
#define W4S 99

__global__ __launch_bounds__(256) void kB(
    const float* __restrict__ S1part, const float* __restrict__ spsum,
    const float* __restrict__ spsq, const float* __restrict__ wcp,
    const float* __restrict__ bc, const float* __restrict__ b_mat,
    const float* __restrict__ h_mat, const float* __restrict__ a_mat,
    const float* __restrict__ noise, const float* __restrict__ indicator,
    const float* __restrict__ cutb, const float* __restrict__ W3,
    const float* __restrict__ b3, const float* __restrict__ W4,
    const float* __restrict__ b4, const float* __restrict__ Wo,
    const float* __restrict__ bo, float* __restrict__ out) {
  __shared__ float W3l[98 * W3S];
  __shared__ float W4l[49 * W4S];
  __shared__ float Wol[10 * 49];
  __shared__ float b3l[98], b4l[49], bol[10];
  __shared__ float cutl[32], coefl[256], konstl[32], wcs[256];
  __shared__ float psum[8][33], psq[8][33];
  __shared__ float mvals[8], vvals[8];
  __shared__ float sh_gm, sh_inv;
  __shared__ float offs[D_][J_];
  __shared__ float h1[8][32];
  __shared__ float h2[8][100];
  __shared__ float h3[8][52];
  __shared__ float lg[8][10];
  __shared__ float lsel[8];

  const int tid = threadIdx.x;

  for (int idx = tid; idx < 98 * 32; idx += 256) {
    int o = idx >> 5, j = idx & 31;
    W3l[o * W3S + j] = W3[idx];
  }
  for (int idx = tid; idx < 49 * 98; idx += 256) {
    int o = idx / 98, k = idx - o * 98;
    W4l[o * W4S + k] = W4[idx];
  }
  for (int idx = tid; idx < 490; idx += 256) Wol[idx] = Wo[idx];
  if (tid < 98) b3l[tid] = b3[tid];
  if (tid < 49) b4l[tid] = b4[tid];
  if (tid < 10) bol[tid] = bo[tid];
  if (tid < 32) cutl[tid] = cutb[tid];

  // wcsum finalize: tid = d*32+j
  {
    float s = 0.0f;
    const float* p = wcp + (size_t)tid * 8;
#pragma unroll
    for (int o8 = 0; o8 < 8; ++o8) s += p[o8];
    wcs[tid] = s;
  }

  // stats reduce: slot = id*4 + w, id = (bg*4+oc)*8 + d
  {
    int dd = tid >> 5, i = tid & 31;
    float s = 0.0f, q = 0.0f;
#pragma unroll
    for (int m = 0; m < 4; ++m) {
      int k = i + m * 32;  // (bg*4+oc) in [0,128)
      int base = (k * 8 + dd) * 4;
#pragma unroll
      for (int ww = 0; ww < 4; ++ww) {
        s += spsum[base + ww];
        q += spsq[base + ww];
      }
    }
    psum[dd][i] = s;
    psq[dd][i] = q;
  }
  __syncthreads();
  if (tid < 8) {
    float s = 0.0f, q = 0.0f;
#pragma unroll
    for (int i = 0; i < 32; ++i) {
      s += psum[tid][i];
      q += psq[tid][i];
    }
    const float inv_cnt = 1.0f / ((float)B_ * (float)NXT_);
    float m = s * inv_cnt;
    mvals[tid] = m;
    vvals[tid] = q * inv_cnt - m * m;
  }
  __syncthreads();
  if (tid == 0) {
    float gm = 0.0f, gv = 0.0f;
    for (int dd = 0; dd < 8; ++dd) {
      gm += mvals[dd];
      gv += vvals[dd];
    }
    gm *= 0.125f;
    gv *= 0.125f;
    sh_gm = gm;
    sh_inv = 1.0f / sqrtf(gv + 1e-6f);
  }
  __syncthreads();
  {
    int dd = tid >> 5, j = tid & 31;
    float hs[A_] = {0, 0, 0, 0, 0};
    for (int k = 0; k < K_; ++k) {
      float indv = indicator[j * K_ + k];
      if (indv != 0.0f) {
        const float* hp = h_mat + ((size_t)dd * K_ + k) * A_;
#pragma unroll
        for (int a = 0; a < A_; ++a) hs[a] = fmaf(indv, hp[a], hs[a]);
      }
    }
    float hv = 0.0f;
#pragma unroll
    for (int a = 0; a < A_; ++a) hv = fmaf(hs[a], a_mat[j * A_ + a], hv);
    float c = b_mat[dd * J_ + j] * hv;
    coefl[tid] = c * sh_inv;
    offs[dd][j] = c * (bc[dd * J_ + j] - sh_gm * wcs[tid] * sh_inv);
  }
  __syncthreads();
  if (tid < J_) {
    float nz = 0.0f;
#pragma unroll
    for (int a = 0; a < A_; ++a)
      nz = fmaf(a_mat[tid * A_ + a], noise[tid * A_ + a], nz);
    float s = nz;
#pragma unroll
    for (int dd = 0; dd < D_; ++dd) s += offs[dd][tid];
    konstl[tid] = s;
  }
  __syncthreads();

  const int row = tid >> 5, lane = tid & 31;
  const int b = blockIdx.x * 8 + row;  // 125*8 = 1000 exactly

  float rsum = konstl[lane];
#pragma unroll
  for (int dd = 0; dd < D_; ++dd) {
    float s = 0.0f;
#pragma unroll
    for (int p = 0; p < 4; ++p)
      s += S1part[(((size_t)p * 1024 + b) * 8 + dd) * 32 + lane];
    rsum = fmaf(coefl[dd * J_ + lane], s, rsum);
  }
  h1[row][lane] = fmaxf(rsum + cutl[lane], 0.0f);
  __syncthreads();

  for (int o = lane; o < 98; o += 32) {
    float a = b3l[o];
#pragma unroll
    for (int j = 0; j < 32; ++j) a = fmaf(h1[row][j], W3l[o * W3S + j], a);
    h2[row][o] = fmaxf(a, 0.0f);
  }
  __syncthreads();

  for (int o = lane; o < 49; o += 32) {
    float a = b4l[o];
    for (int k = 0; k < 98; ++k) a = fmaf(h2[row][k], W4l[o * W4S + k], a);
    h3[row][o] = fmaxf(a, 0.0f);
  }
  __syncthreads();

  if (lane < 10) {
    float a = bol[lane];
#pragma unroll
    for (int k = 0; k < 49; ++k) a = fmaf(h3[row][k], Wol[lane * 49 + k], a);
    lg[row][lane] = a;
  }
  __syncthreads();
  if (lane == 0) {
    float mx = lg[row][0];
    for (int i = 1; i < 10; ++i) mx = fmaxf(mx, lg[row][i]);
    float se = 0.0f;
    for (int i = 0; i < 10; ++i) se += expf(lg[row][i] - mx);
    lsel[row] = mx + logf(se);
  }
  __syncthreads();
  if (lane < 10) out[(size_t)b * 10 + lane] = lg[row][lane] - lsel[row];
}

extern "C" void kernel_launch(void* const* d_in, const int* in_sizes, int n_in,
                              void* d_out, int out_size, void* d_ws,
                              size_t ws_size, hipStream_t stream) {
  const float* x = (const float*)d_in[0];
  const float* W1 = (const float*)d_in[1];
  const float* b1 = (const float*)d_in[2];
  const float* Wc = (const float*)d_in[3];
  const float* bc = (const float*)d_in[4];
  const float* cutb = (const float*)d_in[5];
  const float* bmat = (const float*)d_in[6];
  const float* hmat = (const float*)d_in[7];
  const float* amat = (const float*)d_in[8];
  const float* noise = (const float*)d_in[9];
  const float* W3 = (const float*)d_in[10];
  const float* b3 = (const float*)d_in[11];
  const float* W4 = (const float*)d_in[12];
  const float* b4 = (const float*)d_in[13];
  const float* Wo = (const float*)d_in[14];
  const float* bo = (const float*)d_in[15];
  const float* ind = (const float*)d_in[16];

  float* ws = (float*)d_ws;
  float* S1part = ws;                                     // [0, 1048576)
  unsigned short* w1a = (unsigned short*)(ws + 1048576);  // 917,504 us
  unsigned short* xa = (unsigned short*)(ws + 1966080);   // 458,752 us (x2B)
  unsigned short* wca = (unsigned short*)(ws + 2424832);  // 524,288 us
  float* spsum = ws + 2686976;                            // 4096
  float* spsq = ws + 2691072;                             // 4096
  float* wcp = ws + 2695168;                              // 2048

  kcvt<<<832, 256, 0, stream>>>(x, W1, b1, Wc, w1a, xa, wca, wcp);
  k1<<<1024, 256, 0, stream>>>(w1a, xa, wca, S1part, spsum, spsq);
  kB<<<125, 256, 0, stream>>>(S1part, spsum, spsq, wcp, bc, bmat, hmat, amat,
                              noise, ind, cutb, W3, b3, W4, b4, Wo, bo,
                              (float*)d_out);
}